// Round 9
// baseline (2319.636 us; speedup 1.0000x reference)
//
#include <hip/hip_runtime.h>

typedef _Float16 half8  __attribute__((ext_vector_type(8)));
typedef _Float16 half4h __attribute__((ext_vector_type(4)));
typedef _Float16 half2h __attribute__((ext_vector_type(2)));
typedef float    floatx4 __attribute__((ext_vector_type(4)));
typedef float    floatx2 __attribute__((ext_vector_type(2)));
typedef unsigned int uintx4 __attribute__((ext_vector_type(4)));

#define DEV __device__ __forceinline__

DEV float sigmoid_(float x) { return __builtin_amdgcn_rcpf(1.f + __expf(-x)); }
DEV float tanh_(float x) {
  float e = __expf(-2.f * fabsf(x));
  float t = (1.f - e) * __builtin_amdgcn_rcpf(1.f + e);
  return x < 0.f ? -t : t;
}

// ---------------------------------------------------------------- cast f32->f16
__global__ void cast_f2h(const float* __restrict__ in, _Float16* __restrict__ outp, int n4) {
  int i = blockIdx.x * 256 + threadIdx.x;
  if (i < n4) {
    floatx4 v = ((const floatx4*)in)[i];
    half4h o;
    o[0] = (_Float16)v[0]; o[1] = (_Float16)v[1]; o[2] = (_Float16)v[2]; o[3] = (_Float16)v[3];
    ((half4h*)outp)[i] = o;
  }
}

// ---------------------------------------------------------------- generic f16 GEMM
// C[M,N] = A[M,K] @ Bt[N,K]^T (+ colbias[col]) (+ rowbias[row]); 128x128 tile, BK=64.
// Batched via blockIdx.z with element strides sA,sB,sC.
__launch_bounds__(256, 2)
__global__ void gemm_f16(const _Float16* __restrict__ A, int lda, long long sA,
                         const _Float16* __restrict__ Bt, int ldb, long long sB,
                         void* __restrict__ Cv, int ldc, long long sC, int c_f16,
                         const float* __restrict__ colbias,
                         const float* __restrict__ rowbias, int K)
{
  __shared__ __align__(16) _Float16 As[128 * 64];
  __shared__ __align__(16) _Float16 Bs[128 * 64];
  int m0 = blockIdx.y * 128, n0 = blockIdx.x * 128;
  int z = blockIdx.z;
  const _Float16* Ab = A + (size_t)z * sA;
  const _Float16* Bb = Bt + (size_t)z * sB;
  int tid = threadIdx.x;
  int wave = tid >> 6, lane = tid & 63;
  int ln = lane & 15, lg = lane >> 4;
  int wr = wave >> 1, wcq = wave & 1;
  int srow = wave * 32 + (lane >> 3);
  int scol = (lane & 7) * 8;
  const _Float16* ga = Ab + (size_t)(m0 + srow) * lda + scol;
  const _Float16* gb = Bb + (size_t)(n0 + srow) * ldb + scol;

  floatx4 acc[4][4];
#pragma unroll
  for (int i = 0; i < 4; ++i)
#pragma unroll
    for (int j = 0; j < 4; ++j) acc[i][j] = (floatx4){0.f, 0.f, 0.f, 0.f};

  uintx4 va[4], vb[4];
#pragma unroll
  for (int i = 0; i < 4; ++i) {
    va[i] = *(const uintx4*)(ga + (size_t)i * 8 * lda);
    vb[i] = *(const uintx4*)(gb + (size_t)i * 8 * ldb);
  }
  for (int k0 = 0; k0 < K; k0 += 64) {
#pragma unroll
    for (int i = 0; i < 4; ++i) {
      *(uintx4*)&As[(srow + i * 8) * 64 + scol] = va[i];
      *(uintx4*)&Bs[(srow + i * 8) * 64 + scol] = vb[i];
    }
    __syncthreads();
    if (k0 + 64 < K) {
#pragma unroll
      for (int i = 0; i < 4; ++i) {
        va[i] = *(const uintx4*)(ga + (size_t)i * 8 * lda + k0 + 64);
        vb[i] = *(const uintx4*)(gb + (size_t)i * 8 * ldb + k0 + 64);
      }
    }
#pragma unroll
    for (int kk = 0; kk < 64; kk += 32) {
      half8 af[4], bf[4];
#pragma unroll
      for (int i = 0; i < 4; ++i) af[i] = *(const half8*)&As[(wr * 64 + i * 16 + ln) * 64 + kk + lg * 8];
#pragma unroll
      for (int j = 0; j < 4; ++j) bf[j] = *(const half8*)&Bs[(wcq * 64 + j * 16 + ln) * 64 + kk + lg * 8];
#pragma unroll
      for (int i = 0; i < 4; ++i)
#pragma unroll
        for (int j = 0; j < 4; ++j)
          acc[i][j] = __builtin_amdgcn_mfma_f32_16x16x32_f16(af[i], bf[j], acc[i][j], 0, 0, 0);
    }
    __syncthreads();
  }
  size_t zc = (size_t)z * sC;
#pragma unroll
  for (int i = 0; i < 4; ++i) {
    int row0 = m0 + wr * 64 + i * 16 + lg * 4;
#pragma unroll
    for (int j = 0; j < 4; ++j) {
      int col = n0 + wcq * 64 + j * 16 + ln;
      float cb = colbias ? colbias[col] : 0.f;
#pragma unroll
      for (int r = 0; r < 4; ++r) {
        int row = row0 + r;
        float v = acc[i][j][r] + cb;
        if (rowbias) v += rowbias[row];
        if (c_f16) ((_Float16*)Cv)[zc + (size_t)row * ldc + col] = (_Float16)v;
        else       ((float*)Cv)[zc + (size_t)row * ldc + col] = v;
      }
    }
  }
}

// ---------------------------------------------------------------- GRU recurrence
// 18 blocks: 0..7 doc fwd (8 seq each), 8..15 doc bwd, 16 q fwd, 17 q bwd.
// r8 post-mortem: toolchain pins the budget at 128 VGPR/wave (4 waves/EU) for
// any WG size; launch_bounds/amdgpu_waves_per_eu could not raise it. So fit
// 128: 1024 threads = 16 waves, each wave owns 3 n-tiles x 8 k-tiles of W_hh
// = 24 half8 = 96 VGPR. b_hh folded into the MFMA accumulator init (exact:
// torch n-gate = tanh(xn + r*(h@W+b_hh)) and hp here includes b_hh).
// Whole W_hh (393KB f16) is register-resident across the CU's 2048-reg file.
__launch_bounds__(1024)
__global__ void gru_k(const float* __restrict__ wq_hh, const float* __restrict__ bq_hh,
                      const float* __restrict__ wd_hh, const float* __restrict__ bd_hh,
                      const float* __restrict__ q_h0v, const float* __restrict__ d_h0v,
                      const _Float16* __restrict__ xpq, const _Float16* __restrict__ xpd,
                      float* __restrict__ q_ctx, _Float16* __restrict__ d_ctx)
{
  __shared__ __align__(16) float hp[8 * 768];
  __shared__ __align__(16) float hf[8 * 256];
  __shared__ __align__(16) _Float16 ha[16 * 256];

  int g = blockIdx.x;
  int isq = g >= 16;
  int dir = isq ? (g - 16) : (g >> 3);
  int sbase = isq ? 0 : (g & 7) * 8;
  int S = isq ? 1 : 8;
  int T = isq ? 256 : 512;
  const float* Whh = (isq ? wq_hh : wd_hh) + (size_t)dir * 768 * 256;
  const float* bhh = (isq ? bq_hh : bd_hh) + dir * 768;
  const float* h0  = (isq ? q_h0v : d_h0v) + dir * 256;
  const _Float16* xp = (isq ? xpq : xpd + (size_t)sbase * 512 * 1536) + dir * 768;

  int tid = threadIdx.x;
  int wave = tid >> 6, lane = tid & 63;
  int ln = lane & 15, lg = lane >> 4;

  // weight fragments: wave covers n-tiles wave*3..wave*3+2; each lane holds
  // B[k=(lg*8..+7)][n=tile*16+ln] = Whh[n][k] for 8 k-tiles of 32.
  half8 bw[3][8];
  float bias[3];
#pragma unroll
  for (int nt = 0; nt < 3; ++nt) {
    int n = (wave * 3 + nt) * 16 + ln;
    bias[nt] = bhh[n];
#pragma unroll
    for (int kt = 0; kt < 8; ++kt) {
      const floatx4* wp = (const floatx4*)(Whh + (size_t)n * 256 + kt * 32 + lg * 8);
      floatx4 w0 = wp[0], w1 = wp[1];
      half8 hw;
      hw[0] = (_Float16)w0[0]; hw[1] = (_Float16)w0[1]; hw[2] = (_Float16)w0[2]; hw[3] = (_Float16)w0[3];
      hw[4] = (_Float16)w1[0]; hw[5] = (_Float16)w1[1]; hw[6] = (_Float16)w1[2]; hw[7] = (_Float16)w1[3];
      bw[nt][kt] = hw;
    }
  }
  // init h (all seqs share h0); ha is XOR-swizzled by 16B granule within each row.
  if (tid < 256) {
    float v = h0[tid];
    _Float16 hv = (_Float16)v;
    int gq = tid >> 3, wi = tid & 7;
#pragma unroll
    for (int s = 0; s < 8; ++s) {
      hf[s * 256 + tid] = v;
      ha[s * 256 + ((gq ^ s) * 8) + wi] = hv;
    }
  }
  for (int i = tid; i < 2048; i += 1024) ha[2048 + i] = (_Float16)0.f;  // rows 8..15
  __syncthreads();

  int s_g = tid >> 7;          // seq handled in gate phase (2 elems/thread)
  int i0 = (tid & 127) * 2;
  int gact = tid < S * 128;
  int gq0 = i0 >> 3, gw0 = i0 & 7;
  int srow = isq ? 0 : s_g;

  for (int t = 0; t < T; ++t) {
    int teff = dir ? (T - 1 - t) : t;
    // issue x-projection loads early; MFMA phase hides the latency
    half2h xr_c, xz_c, xn_c;
    if (gact) {
      const _Float16* xrp = xp + ((size_t)srow * 512 + (size_t)teff) * 1536 + i0;
      xr_c = *(const half2h*)(xrp);
      xz_c = *(const half2h*)(xrp + 256);
      xn_c = *(const half2h*)(xrp + 512);
    }
    floatx4 acc[3];
#pragma unroll
    for (int nt = 0; nt < 3; ++nt) acc[nt] = (floatx4){bias[nt], bias[nt], bias[nt], bias[nt]};
#pragma unroll
    for (int kt = 0; kt < 8; ++kt) {
      half8 af;
      if (ln < 8)  // rows 8..15 of the A tile are unused -> halve LDS traffic
        af = *(const half8*)&ha[ln * 256 + (((kt * 4 + lg) ^ ln) * 8)];
#pragma unroll
      for (int nt = 0; nt < 3; ++nt)
        acc[nt] = __builtin_amdgcn_mfma_f32_16x16x32_f16(af, bw[nt][kt], acc[nt], 0, 0, 0);
    }
    if (lane < 32) {  // C rows 0..7 live on lanes 0..31
#pragma unroll
      for (int nt = 0; nt < 3; ++nt) {
        int n = (wave * 3 + nt) * 16 + ln;
#pragma unroll
        for (int r = 0; r < 4; ++r)
          hp[(lg * 4 + r) * 768 + n] = acc[nt][r];
      }
    }
    __syncthreads();
    if (gact) {
      floatx2 hr2 = *(const floatx2*)&hp[s_g * 768 + i0];
      floatx2 hz2 = *(const floatx2*)&hp[s_g * 768 + 256 + i0];
      floatx2 hn2 = *(const floatx2*)&hp[s_g * 768 + 512 + i0];
      floatx2 hv2 = *(const floatx2*)&hf[s_g * 256 + i0];
      floatx2 h2;
#pragma unroll
      for (int u = 0; u < 2; ++u) {
        float r  = sigmoid_((float)xr_c[u] + hr2[u]);
        float zz = sigmoid_((float)xz_c[u] + hz2[u]);
        float nn = tanh_((float)xn_c[u] + r * hn2[u]);
        h2[u] = (1.f - zz) * nn + zz * hv2[u];
      }
      *(floatx2*)&hf[s_g * 256 + i0] = h2;
      half2h hh;
      hh[0] = (_Float16)h2[0]; hh[1] = (_Float16)h2[1];
      *(half2h*)&ha[s_g * 256 + ((gq0 ^ s_g) * 8) + gw0] = hh;
      if (isq) {
        *(floatx2*)&q_ctx[(size_t)teff * 512 + dir * 256 + i0] = h2;
      } else {
        *(half2h*)&d_ctx[((size_t)(sbase + s_g) * 512 + (size_t)teff) * 512 + dir * 256 + i0] = hh;
      }
    }
    __syncthreads();
  }
}

// ---------------------------------------------------------------- small prep kernels
__global__ void qprep_k(const float* __restrict__ qctx, const float* __restrict__ wc,
                        _Float16* __restrict__ qwc, _Float16* __restrict__ qT, float* __restrict__ avec) {
  int q = blockIdx.x, h = threadIdx.x;  // 256 blocks x 512 threads
  float v = qctx[q * 512 + h];
  qwc[q * 512 + h] = (_Float16)(v * wc[1024 + h]);
  qT[h * 256 + q] = (_Float16)v;
  float p = v * wc[h];
  __shared__ float red[8];
#pragma unroll
  for (int o = 32; o; o >>= 1) p += __shfl_xor(p, o);
  if ((h & 63) == 0) red[h >> 6] = p;
  __syncthreads();
  if (h < 8) {
    float tt = red[h];
#pragma unroll
    for (int o = 4; o; o >>= 1) tt += __shfl_xor(tt, o);
    if (h == 0) avec[q] = tt;
  }
}

__global__ void bvec_k(const _Float16* __restrict__ dctx, const float* __restrict__ wc, float* __restrict__ bv) {
  int row = blockIdx.x * 4 + (threadIdx.x >> 6);
  int lane = threadIdx.x & 63;
  const _Float16* p = dctx + (size_t)row * 512;
  float s = 0.f;
#pragma unroll
  for (int i = 0; i < 8; ++i) s += (float)p[lane + i * 64] * wc[512 + lane + i * 64];
#pragma unroll
  for (int o = 32; o; o >>= 1) s += __shfl_xor(s, o);
  if (lane == 0) bv[row] = s;
}

__global__ void reduce_rows(const float* __restrict__ sxy, float* __restrict__ rmax, float* __restrict__ rsum) {
  int row = blockIdx.x * 4 + (threadIdx.x >> 6);
  int lane = threadIdx.x & 63;
  const float* p = sxy + (size_t)row * 256;
  float v0 = p[lane], v1 = p[lane + 64], v2 = p[lane + 128], v3 = p[lane + 192];
  float m = fmaxf(fmaxf(v0, v1), fmaxf(v2, v3));
#pragma unroll
  for (int o = 32; o; o >>= 1) m = fmaxf(m, __shfl_xor(m, o));
  float s = __expf(v0 - m) + __expf(v1 - m) + __expf(v2 - m) + __expf(v3 - m);
#pragma unroll
  for (int o = 32; o; o >>= 1) s += __shfl_xor(s, o);
  if (lane == 0) { rmax[row] = m; rsum[row] = s; }
}

__global__ void reduce_cols(const float* __restrict__ sxy, float* __restrict__ cmax, float* __restrict__ csum) {
  int n = blockIdx.x, q = threadIdx.x;  // 64 x 256
  const float* p = sxy + (size_t)n * 131072 + q;
  float m = -3.0e38f, s = 0.f;
  for (int l = 0; l < 512; l += 4) {
    float v0 = p[(size_t)l * 256], v1 = p[(size_t)(l + 1) * 256];
    float v2 = p[(size_t)(l + 2) * 256], v3 = p[(size_t)(l + 3) * 256];
    float m4 = fmaxf(fmaxf(v0, v1), fmaxf(v2, v3));
    float nm = fmaxf(m, m4);
    s = s * __expf(m - nm) + __expf(v0 - nm) + __expf(v1 - nm) + __expf(v2 - nm) + __expf(v3 - nm);
    m = nm;
  }
  cmax[n * 256 + q] = m;
  csum[n * 256 + q] = s;
}

__global__ void probs_k(const float* __restrict__ sxy, const float* __restrict__ rmax, const float* __restrict__ rsum,
                        const float* __restrict__ cmax, const float* __restrict__ csum,
                        _Float16* __restrict__ sd2q, _Float16* __restrict__ sq2d) {
  size_t e4 = ((size_t)blockIdx.x * 256 + threadIdx.x) * 4;
  size_t r = e4 >> 8;
  size_t n = e4 >> 17;
  int q0 = (int)(e4 & 255);
  floatx4 v = *(const floatx4*)&sxy[e4];
  float rm = rmax[r], ri = 1.f / rsum[r];
  floatx4 cm = *(const floatx4*)&cmax[(n << 8) + q0];
  floatx4 cs = *(const floatx4*)&csum[(n << 8) + q0];
  half4h o1, o2;
#pragma unroll
  for (int u = 0; u < 4; ++u) {
    o1[u] = (_Float16)(__expf(v[u] - rm) * ri);
    o2[u] = (_Float16)(__expf(v[u] - cm[u]) / cs[u]);
  }
  *(half4h*)&sd2q[e4] = o1;
  *(half4h*)&sq2d[e4] = o2;
}

__global__ void transpose_k(const _Float16* __restrict__ in, _Float16* __restrict__ outp) {
  __shared__ _Float16 tile[32][33];
  int nz = blockIdx.z;
  int l0 = blockIdx.x * 32, h0 = blockIdx.y * 32;
  const _Float16* ip = in + (size_t)nz * 262144;
  _Float16* op = outp + (size_t)nz * 262144;
  int x = threadIdx.x & 31, y = threadIdx.x >> 5;
#pragma unroll
  for (int i = 0; i < 4; ++i) tile[y + i * 8][x] = ip[(size_t)(l0 + y + i * 8) * 512 + h0 + x];
  __syncthreads();
#pragma unroll
  for (int i = 0; i < 4; ++i) op[(size_t)(h0 + y + i * 8) * 512 + l0 + x] = tile[x][y + i * 8];
}

// ---------------------------------------------------------------- launch
extern "C" void kernel_launch(void* const* d_in, const int* in_sizes, int n_in,
                              void* d_out, int out_size, void* d_ws, size_t ws_size,
                              hipStream_t stream) {
  const float* doc   = (const float*)d_in[0];
  const float* ques  = (const float*)d_in[1];
  const float* q_h0  = (const float*)d_in[2];
  const float* d_h0  = (const float*)d_in[3];
  const float* wq_ih = (const float*)d_in[4];
  const float* wq_hh = (const float*)d_in[5];
  const float* bq_ih = (const float*)d_in[6];
  const float* bq_hh = (const float*)d_in[7];
  const float* wd_ih = (const float*)d_in[8];
  const float* wd_hh = (const float*)d_in[9];
  const float* bd_ih = (const float*)d_in[10];
  const float* bd_hh = (const float*)d_in[11];
  const float* wc    = (const float*)d_in[12];
  float* out = (float*)d_out;
  char* ws = (char*)d_ws;

  // workspace layout (peak ~133.5 MiB, regions reused over time)
  _Float16* xd   = (_Float16*)(ws + 0);            // 33,554,432 B  (later: dctx, then sd2q|sq2d)
  _Float16* xq   = (_Float16*)(ws + 33554432);     //    262,144
  _Float16* wdI  = (_Float16*)(ws + 33816576);     //  1,572,864
  _Float16* wqI  = (_Float16*)(ws + 35389440);     //  1,572,864
  _Float16* xpd  = (_Float16*)(ws + 36962304);     // 100,663,296  (later: sxy | mbuf | dT)
  _Float16* xpq  = (_Float16*)(ws + 137625600);    //    786,432
  float*    qctx = (float*)   (ws + 138412032);    //    524,288
  _Float16* qT   = (_Float16*)(ws + 138936320);    //    262,144
  _Float16* qwc  = (_Float16*)(ws + 139198464);    //    262,144
  float*    avec = (float*)   (ws + 139460608);    //      1,024
  float*    bvec = (float*)   (ws + 139461632);    //    131,072
  float*    rmax = (float*)   (ws + 139592704);    //    131,072
  float*    rsum = (float*)   (ws + 139723776);    //    131,072
  float*    cmax = (float*)   (ws + 139854848);    //     65,536
  float*    csum = (float*)   (ws + 139920384);    //     65,536
  // aliases
  _Float16* dctx = (_Float16*)(ws + 0);                       // after xp-GEMM
  _Float16* sd2q = (_Float16*)(ws + 0);                       // after transpose
  _Float16* sq2d = (_Float16*)(ws + 16777216);
  float*    sxy  = (float*)   (ws + 36962304);                // after GRU
  _Float16* mbuf = (_Float16*)(ws + 36962304 + 33554432);
  _Float16* dT   = (_Float16*)(ws + 36962304 + 67108864);

  // 1) casts to f16
  cast_f2h<<<dim3(16384), dim3(256), 0, stream>>>(doc,   xd,  4194304);
  cast_f2h<<<dim3(128),   dim3(256), 0, stream>>>(ques,  xq,  32768);
  cast_f2h<<<dim3(768),   dim3(256), 0, stream>>>(wd_ih, wdI, 196608);
  cast_f2h<<<dim3(768),   dim3(256), 0, stream>>>(wq_ih, wqI, 196608);

  // 2) input transforms: xp = x @ W_ih^T + b_ih   (both directions stacked: N=1536)
  gemm_f16<<<dim3(12, 2, 1),   dim3(256), 0, stream>>>(xq, 512, 0, wqI, 512, 0, xpq, 1536, 0, 1, bq_ih, nullptr, 512);
  gemm_f16<<<dim3(12, 256, 1), dim3(256), 0, stream>>>(xd, 512, 0, wdI, 512, 0, xpd, 1536, 0, 1, bd_ih, nullptr, 512);

  // 3) GRU recurrence (writes dctx f16 over xd region, qctx f32)
  gru_k<<<dim3(18), dim3(1024), 0, stream>>>(wq_hh, bq_hh, wd_hh, bd_hh, q_h0, d_h0, xpq, xpd, qctx, dctx);

  // 4) attention prep
  qprep_k<<<dim3(256), dim3(512), 0, stream>>>(qctx, wc, qwc, qT, avec);
  bvec_k<<<dim3(8192), dim3(256), 0, stream>>>(dctx, wc, bvec);

  // 5) logits sxy[n,l,q] = d_ctx . (q_ctx*wc_qd) + a[q] + b[n,l]   (f32 out)
  gemm_f16<<<dim3(2, 256, 1), dim3(256), 0, stream>>>(dctx, 512, 0, qwc, 512, 0, sxy, 256, 0, 0, avec, bvec, 512);

  // 6) d_ctx^T per sentence (needed for aq2d; must precede probs which overwrites dctx)
  transpose_k<<<dim3(16, 16, 64), dim3(256), 0, stream>>>(dctx, dT);

  // 7) softmax reductions + probability tensors (f16)
  reduce_rows<<<dim3(8192), dim3(256), 0, stream>>>(sxy, rmax, rsum);
  reduce_cols<<<dim3(64),   dim3(256), 0, stream>>>(sxy, cmax, csum);
  probs_k<<<dim3(8192), dim3(256), 0, stream>>>(sxy, rmax, rsum, cmax, csum, sd2q, sq2d);

  // 8) ad2q = sd2q @ q_ctx   -> out[:, 0:512]
  gemm_f16<<<dim3(4, 256, 1), dim3(256), 0, stream>>>(sd2q, 256, 0, qT, 256, 0, out, 1024, 0, 0, nullptr, nullptr, 256);

  // 9) m[n] = sd2q[n] @ sq2d[n]^T  (f16)
  gemm_f16<<<dim3(4, 4, 64), dim3(256), 0, stream>>>(sd2q, 256, 131072, sq2d, 256, 131072, mbuf, 512, 262144, 1, nullptr, nullptr, 256);

  // 10) aq2d[n] = m[n] @ d_ctx[n]  -> out[:, 512:1024]
  gemm_f16<<<dim3(4, 4, 64), dim3(256), 0, stream>>>(mbuf, 512, 262144, dT, 512, 262144, out + 512, 1024, 524288, 0, nullptr, nullptr, 512);
}

// Round 10
// 1584.260 us; speedup vs baseline: 1.4642x; 1.4642x over previous
//
#include <hip/hip_runtime.h>

typedef _Float16 half8  __attribute__((ext_vector_type(8)));
typedef _Float16 half4h __attribute__((ext_vector_type(4)));
typedef float    floatx4 __attribute__((ext_vector_type(4)));
typedef unsigned int uintx4 __attribute__((ext_vector_type(4)));

#define DEV __device__ __forceinline__

DEV float sigmoid_(float x) { return __builtin_amdgcn_rcpf(1.f + __expf(-x)); }
DEV float tanh_(float x) {
  float e = __expf(-2.f * fabsf(x));
  float t = (1.f - e) * __builtin_amdgcn_rcpf(1.f + e);
  return x < 0.f ? -t : t;
}

// ---------------------------------------------------------------- cast f32->f16
__global__ void cast_f2h(const float* __restrict__ in, _Float16* __restrict__ outp, int n4) {
  int i = blockIdx.x * 256 + threadIdx.x;
  if (i < n4) {
    floatx4 v = ((const floatx4*)in)[i];
    half4h o;
    o[0] = (_Float16)v[0]; o[1] = (_Float16)v[1]; o[2] = (_Float16)v[2]; o[3] = (_Float16)v[3];
    ((half4h*)outp)[i] = o;
  }
}

// ---------------------------------------------------------------- generic f16 GEMM
// C[M,N] = A[M,K] @ Bt[N,K]^T (+ colbias[col]) (+ rowbias[row]); 128x128 tile, BK=64.
// Batched via blockIdx.z with element strides sA,sB,sC.
__launch_bounds__(256, 2)
__global__ void gemm_f16(const _Float16* __restrict__ A, int lda, long long sA,
                         const _Float16* __restrict__ Bt, int ldb, long long sB,
                         void* __restrict__ Cv, int ldc, long long sC, int c_f16,
                         const float* __restrict__ colbias,
                         const float* __restrict__ rowbias, int K)
{
  __shared__ __align__(16) _Float16 As[128 * 64];
  __shared__ __align__(16) _Float16 Bs[128 * 64];
  int m0 = blockIdx.y * 128, n0 = blockIdx.x * 128;
  int z = blockIdx.z;
  const _Float16* Ab = A + (size_t)z * sA;
  const _Float16* Bb = Bt + (size_t)z * sB;
  int tid = threadIdx.x;
  int wave = tid >> 6, lane = tid & 63;
  int ln = lane & 15, lg = lane >> 4;
  int wr = wave >> 1, wcq = wave & 1;
  int srow = wave * 32 + (lane >> 3);
  int scol = (lane & 7) * 8;
  const _Float16* ga = Ab + (size_t)(m0 + srow) * lda + scol;
  const _Float16* gb = Bb + (size_t)(n0 + srow) * ldb + scol;

  floatx4 acc[4][4];
#pragma unroll
  for (int i = 0; i < 4; ++i)
#pragma unroll
    for (int j = 0; j < 4; ++j) acc[i][j] = (floatx4){0.f, 0.f, 0.f, 0.f};

  uintx4 va[4], vb[4];
#pragma unroll
  for (int i = 0; i < 4; ++i) {
    va[i] = *(const uintx4*)(ga + (size_t)i * 8 * lda);
    vb[i] = *(const uintx4*)(gb + (size_t)i * 8 * ldb);
  }
  for (int k0 = 0; k0 < K; k0 += 64) {
#pragma unroll
    for (int i = 0; i < 4; ++i) {
      *(uintx4*)&As[(srow + i * 8) * 64 + scol] = va[i];
      *(uintx4*)&Bs[(srow + i * 8) * 64 + scol] = vb[i];
    }
    __syncthreads();
    if (k0 + 64 < K) {
#pragma unroll
      for (int i = 0; i < 4; ++i) {
        va[i] = *(const uintx4*)(ga + (size_t)i * 8 * lda + k0 + 64);
        vb[i] = *(const uintx4*)(gb + (size_t)i * 8 * ldb + k0 + 64);
      }
    }
#pragma unroll
    for (int kk = 0; kk < 64; kk += 32) {
      half8 af[4], bf[4];
#pragma unroll
      for (int i = 0; i < 4; ++i) af[i] = *(const half8*)&As[(wr * 64 + i * 16 + ln) * 64 + kk + lg * 8];
#pragma unroll
      for (int j = 0; j < 4; ++j) bf[j] = *(const half8*)&Bs[(wcq * 64 + j * 16 + ln) * 64 + kk + lg * 8];
#pragma unroll
      for (int i = 0; i < 4; ++i)
#pragma unroll
        for (int j = 0; j < 4; ++j)
          acc[i][j] = __builtin_amdgcn_mfma_f32_16x16x32_f16(af[i], bf[j], acc[i][j], 0, 0, 0);
    }
    __syncthreads();
  }
  size_t zc = (size_t)z * sC;
#pragma unroll
  for (int i = 0; i < 4; ++i) {
    int row0 = m0 + wr * 64 + i * 16 + lg * 4;
#pragma unroll
    for (int j = 0; j < 4; ++j) {
      int col = n0 + wcq * 64 + j * 16 + ln;
      float cb = colbias ? colbias[col] : 0.f;
#pragma unroll
      for (int r = 0; r < 4; ++r) {
        int row = row0 + r;
        float v = acc[i][j][r] + cb;
        if (rowbias) v += rowbias[row];
        if (c_f16) ((_Float16*)Cv)[zc + (size_t)row * ldc + col] = (_Float16)v;
        else       ((float*)Cv)[zc + (size_t)row * ldc + col] = v;
      }
    }
  }
}

// ---------------------------------------------------------------- GRU recurrence
// 18 blocks: 0..7 doc fwd (8 seq each), 8..15 doc bwd, 16 q fwd, 17 q bwd.
// 512 threads = 8 waves; W_hh f16 register-resident: 6 ntiles x 8 ktiles = 192
// VGPR/wave. r9 post-mortem: the compiler budgets VGPRs for exactly 2 WGs/CU
// (VGPR cap = 65536/T for T=768/512/1024 measured) and ignores launch_bounds /
// waves_per_eu -- so force 1 WG/CU via LDS: pad LDS above 80KB so only one WG
// fits, which lifts the budget to 2 waves/EU = 256 VGPR (mechanism validated
// by the 8-phase GEMM example and m214 attn: 512-thr kernels with >80KB LDS
// get ~250 VGPR on this toolchain).
__launch_bounds__(512, 2)
__global__ void gru_k(const float* __restrict__ wq_hh, const float* __restrict__ bq_hh,
                      const float* __restrict__ wd_hh, const float* __restrict__ bd_hh,
                      const float* __restrict__ q_h0v, const float* __restrict__ d_h0v,
                      const _Float16* __restrict__ xpq, const _Float16* __restrict__ xpd,
                      float* __restrict__ q_ctx, _Float16* __restrict__ d_ctx)
{
  __shared__ __align__(16) float hp[8 * 768];
  __shared__ __align__(16) float hf[8 * 256];
  __shared__ __align__(16) _Float16 ha[16 * 256];
  __shared__ __align__(16) float bl[768];
  __shared__ __align__(16) float lds_pad[10240];   // occupancy limiter: 40KB -> 1 WG/CU

  int g = blockIdx.x;
  int isq = g >= 16;
  int dir = isq ? (g - 16) : (g >> 3);
  int sbase = isq ? 0 : (g & 7) * 8;
  int S = isq ? 1 : 8;
  int T = isq ? 256 : 512;
  const float* Whh = (isq ? wq_hh : wd_hh) + (size_t)dir * 768 * 256;
  const float* bhh = (isq ? bq_hh : bd_hh) + dir * 768;
  const float* h0  = (isq ? q_h0v : d_h0v) + dir * 256;
  const _Float16* xp = (isq ? xpq : xpd + (size_t)sbase * 512 * 1536) + dir * 768;

  int tid = threadIdx.x;
  int wave = tid >> 6, lane = tid & 63;
  int ln = lane & 15, lg = lane >> 4;

  // keep lds_pad alive (g < 18 always; compiler can't prove it)
  if (g >= 18) {
    lds_pad[tid] = (float)tid;
    __syncthreads();
    q_ctx[tid] = lds_pad[511 - tid];
  }

  // load weight fragments: wave covers n-tiles wave*6..wave*6+5; each lane holds
  // B[k=(lg*8..+7)][n=tile*16+ln] = Whh[n][k] for 8 k-tiles of 32.
  half8 bw[6][8];
#pragma unroll
  for (int nt = 0; nt < 6; ++nt) {
    int n = (wave * 6 + nt) * 16 + ln;
#pragma unroll
    for (int kt = 0; kt < 8; ++kt) {
      const floatx4* wp = (const floatx4*)(Whh + (size_t)n * 256 + kt * 32 + lg * 8);
      floatx4 w0 = wp[0], w1 = wp[1];
      half8 hw;
      hw[0] = (_Float16)w0[0]; hw[1] = (_Float16)w0[1]; hw[2] = (_Float16)w0[2]; hw[3] = (_Float16)w0[3];
      hw[4] = (_Float16)w1[0]; hw[5] = (_Float16)w1[1]; hw[6] = (_Float16)w1[2]; hw[7] = (_Float16)w1[3];
      bw[nt][kt] = hw;
    }
  }
  // init h (all seqs share h0); ha is XOR-swizzled by 16B granule within each row.
  if (tid < 256) {
    float v = h0[tid];
    _Float16 hv = (_Float16)v;
    int gq = tid >> 3, wi = tid & 7;
#pragma unroll
    for (int s = 0; s < 8; ++s) {
      hf[s * 256 + tid] = v;
      ha[s * 256 + ((gq ^ s) * 8) + wi] = hv;
    }
  }
  for (int i = tid; i < 2048; i += 512) ha[2048 + i] = (_Float16)0.f;  // rows 8..15
  for (int i = tid; i < 768; i += 512) bl[i] = bhh[i];
  __syncthreads();

  int s_g = tid >> 6;
  int i0 = (tid & 63) * 4;
  int gact = tid < S * 64;
  int gq0 = i0 >> 3, gw0 = i0 & 7;
  int srow = isq ? 0 : s_g;

  for (int t = 0; t < T; ++t) {
    int teff = dir ? (T - 1 - t) : t;
    // issue x-projection loads early; MFMA phase (~500cy) hides the latency
    half4h xr_c, xz_c, xn_c;
    if (gact) {
      const _Float16* xrp = xp + ((size_t)srow * 512 + (size_t)teff) * 1536 + i0;
      xr_c = *(const half4h*)(xrp);
      xz_c = *(const half4h*)(xrp + 256);
      xn_c = *(const half4h*)(xrp + 512);
    }
    floatx4 acc[6];
#pragma unroll
    for (int nt = 0; nt < 6; ++nt) acc[nt] = (floatx4){0.f, 0.f, 0.f, 0.f};
#pragma unroll
    for (int kt = 0; kt < 8; ++kt) {
      half8 af;
      if (ln < 8)  // rows 8..15 of the A tile are unused -> halve LDS traffic
        af = *(const half8*)&ha[ln * 256 + (((kt * 4 + lg) ^ ln) * 8)];
#pragma unroll
      for (int nt = 0; nt < 6; ++nt)
        acc[nt] = __builtin_amdgcn_mfma_f32_16x16x32_f16(af, bw[nt][kt], acc[nt], 0, 0, 0);
    }
    if (lane < 32) {  // C rows 0..7 live on lanes 0..31
#pragma unroll
      for (int nt = 0; nt < 6; ++nt) {
        int n = (wave * 6 + nt) * 16 + ln;
#pragma unroll
        for (int r = 0; r < 4; ++r)
          hp[(lg * 4 + r) * 768 + n] = acc[nt][r];
      }
    }
    __syncthreads();
    if (gact) {
      floatx4 hr4 = *(const floatx4*)&hp[s_g * 768 + i0];
      floatx4 hz4 = *(const floatx4*)&hp[s_g * 768 + 256 + i0];
      floatx4 hn4 = *(const floatx4*)&hp[s_g * 768 + 512 + i0];
      floatx4 hv4 = *(const floatx4*)&hf[s_g * 256 + i0];
      floatx4 br4 = *(const floatx4*)&bl[i0];
      floatx4 bz4 = *(const floatx4*)&bl[256 + i0];
      floatx4 bn4 = *(const floatx4*)&bl[512 + i0];
      floatx4 h2;
#pragma unroll
      for (int u = 0; u < 4; ++u) {
        float r  = sigmoid_((float)xr_c[u] + hr4[u] + br4[u]);
        float zz = sigmoid_((float)xz_c[u] + hz4[u] + bz4[u]);
        float nn = tanh_((float)xn_c[u] + r * (hn4[u] + bn4[u]));
        h2[u] = (1.f - zz) * nn + zz * hv4[u];
      }
      *(floatx4*)&hf[s_g * 256 + i0] = h2;
      half4h hh;
#pragma unroll
      for (int u = 0; u < 4; ++u) hh[u] = (_Float16)h2[u];
      *(half4h*)&ha[s_g * 256 + ((gq0 ^ s_g) * 8) + gw0] = hh;
      if (isq) {
        *(floatx4*)&q_ctx[(size_t)teff * 512 + dir * 256 + i0] = h2;
      } else {
        *(half4h*)&d_ctx[((size_t)(sbase + s_g) * 512 + (size_t)teff) * 512 + dir * 256 + i0] = hh;
      }
    }
    __syncthreads();
  }
}

// ---------------------------------------------------------------- small prep kernels
__global__ void qprep_k(const float* __restrict__ qctx, const float* __restrict__ wc,
                        _Float16* __restrict__ qwc, _Float16* __restrict__ qT, float* __restrict__ avec) {
  int q = blockIdx.x, h = threadIdx.x;  // 256 blocks x 512 threads
  float v = qctx[q * 512 + h];
  qwc[q * 512 + h] = (_Float16)(v * wc[1024 + h]);
  qT[h * 256 + q] = (_Float16)v;
  float p = v * wc[h];
  __shared__ float red[8];
#pragma unroll
  for (int o = 32; o; o >>= 1) p += __shfl_xor(p, o);
  if ((h & 63) == 0) red[h >> 6] = p;
  __syncthreads();
  if (h < 8) {
    float tt = red[h];
#pragma unroll
    for (int o = 4; o; o >>= 1) tt += __shfl_xor(tt, o);
    if (h == 0) avec[q] = tt;
  }
}

__global__ void bvec_k(const _Float16* __restrict__ dctx, const float* __restrict__ wc, float* __restrict__ bv) {
  int row = blockIdx.x * 4 + (threadIdx.x >> 6);
  int lane = threadIdx.x & 63;
  const _Float16* p = dctx + (size_t)row * 512;
  float s = 0.f;
#pragma unroll
  for (int i = 0; i < 8; ++i) s += (float)p[lane + i * 64] * wc[512 + lane + i * 64];
#pragma unroll
  for (int o = 32; o; o >>= 1) s += __shfl_xor(s, o);
  if (lane == 0) bv[row] = s;
}

__global__ void reduce_rows(const float* __restrict__ sxy, float* __restrict__ rmax, float* __restrict__ rsum) {
  int row = blockIdx.x * 4 + (threadIdx.x >> 6);
  int lane = threadIdx.x & 63;
  const float* p = sxy + (size_t)row * 256;
  float v0 = p[lane], v1 = p[lane + 64], v2 = p[lane + 128], v3 = p[lane + 192];
  float m = fmaxf(fmaxf(v0, v1), fmaxf(v2, v3));
#pragma unroll
  for (int o = 32; o; o >>= 1) m = fmaxf(m, __shfl_xor(m, o));
  float s = __expf(v0 - m) + __expf(v1 - m) + __expf(v2 - m) + __expf(v3 - m);
#pragma unroll
  for (int o = 32; o; o >>= 1) s += __shfl_xor(s, o);
  if (lane == 0) { rmax[row] = m; rsum[row] = s; }
}

__global__ void reduce_cols(const float* __restrict__ sxy, float* __restrict__ cmax, float* __restrict__ csum) {
  int n = blockIdx.x, q = threadIdx.x;  // 64 x 256
  const float* p = sxy + (size_t)n * 131072 + q;
  float m = -3.0e38f, s = 0.f;
  for (int l = 0; l < 512; l += 4) {
    float v0 = p[(size_t)l * 256], v1 = p[(size_t)(l + 1) * 256];
    float v2 = p[(size_t)(l + 2) * 256], v3 = p[(size_t)(l + 3) * 256];
    float m4 = fmaxf(fmaxf(v0, v1), fmaxf(v2, v3));
    float nm = fmaxf(m, m4);
    s = s * __expf(m - nm) + __expf(v0 - nm) + __expf(v1 - nm) + __expf(v2 - nm) + __expf(v3 - nm);
    m = nm;
  }
  cmax[n * 256 + q] = m;
  csum[n * 256 + q] = s;
}

__global__ void probs_k(const float* __restrict__ sxy, const float* __restrict__ rmax, const float* __restrict__ rsum,
                        const float* __restrict__ cmax, const float* __restrict__ csum,
                        _Float16* __restrict__ sd2q, _Float16* __restrict__ sq2d) {
  size_t e4 = ((size_t)blockIdx.x * 256 + threadIdx.x) * 4;
  size_t r = e4 >> 8;
  size_t n = e4 >> 17;
  int q0 = (int)(e4 & 255);
  floatx4 v = *(const floatx4*)&sxy[e4];
  float rm = rmax[r], ri = 1.f / rsum[r];
  floatx4 cm = *(const floatx4*)&cmax[(n << 8) + q0];
  floatx4 cs = *(const floatx4*)&csum[(n << 8) + q0];
  half4h o1, o2;
#pragma unroll
  for (int u = 0; u < 4; ++u) {
    o1[u] = (_Float16)(__expf(v[u] - rm) * ri);
    o2[u] = (_Float16)(__expf(v[u] - cm[u]) / cs[u]);
  }
  *(half4h*)&sd2q[e4] = o1;
  *(half4h*)&sq2d[e4] = o2;
}

__global__ void transpose_k(const _Float16* __restrict__ in, _Float16* __restrict__ outp) {
  __shared__ _Float16 tile[32][33];
  int nz = blockIdx.z;
  int l0 = blockIdx.x * 32, h0 = blockIdx.y * 32;
  const _Float16* ip = in + (size_t)nz * 262144;
  _Float16* op = outp + (size_t)nz * 262144;
  int x = threadIdx.x & 31, y = threadIdx.x >> 5;
#pragma unroll
  for (int i = 0; i < 4; ++i) tile[y + i * 8][x] = ip[(size_t)(l0 + y + i * 8) * 512 + h0 + x];
  __syncthreads();
#pragma unroll
  for (int i = 0; i < 4; ++i) op[(size_t)(h0 + y + i * 8) * 512 + l0 + x] = tile[x][y + i * 8];
}

// ---------------------------------------------------------------- launch
extern "C" void kernel_launch(void* const* d_in, const int* in_sizes, int n_in,
                              void* d_out, int out_size, void* d_ws, size_t ws_size,
                              hipStream_t stream) {
  const float* doc   = (const float*)d_in[0];
  const float* ques  = (const float*)d_in[1];
  const float* q_h0  = (const float*)d_in[2];
  const float* d_h0  = (const float*)d_in[3];
  const float* wq_ih = (const float*)d_in[4];
  const float* wq_hh = (const float*)d_in[5];
  const float* bq_ih = (const float*)d_in[6];
  const float* bq_hh = (const float*)d_in[7];
  const float* wd_ih = (const float*)d_in[8];
  const float* wd_hh = (const float*)d_in[9];
  const float* bd_ih = (const float*)d_in[10];
  const float* bd_hh = (const float*)d_in[11];
  const float* wc    = (const float*)d_in[12];
  float* out = (float*)d_out;
  char* ws = (char*)d_ws;

  // workspace layout (peak ~133.5 MiB, regions reused over time)
  _Float16* xd   = (_Float16*)(ws + 0);            // 33,554,432 B  (later: dctx, then sd2q|sq2d)
  _Float16* xq   = (_Float16*)(ws + 33554432);     //    262,144
  _Float16* wdI  = (_Float16*)(ws + 33816576);     //  1,572,864
  _Float16* wqI  = (_Float16*)(ws + 35389440);     //  1,572,864
  _Float16* xpd  = (_Float16*)(ws + 36962304);     // 100,663,296  (later: sxy | mbuf | dT)
  _Float16* xpq  = (_Float16*)(ws + 137625600);    //    786,432
  float*    qctx = (float*)   (ws + 138412032);    //    524,288
  _Float16* qT   = (_Float16*)(ws + 138936320);    //    262,144
  _Float16* qwc  = (_Float16*)(ws + 139198464);    //    262,144
  float*    avec = (float*)   (ws + 139460608);    //      1,024
  float*    bvec = (float*)   (ws + 139461632);    //    131,072
  float*    rmax = (float*)   (ws + 139592704);    //    131,072
  float*    rsum = (float*)   (ws + 139723776);    //    131,072
  float*    cmax = (float*)   (ws + 139854848);    //     65,536
  float*    csum = (float*)   (ws + 139920384);    //     65,536
  // aliases
  _Float16* dctx = (_Float16*)(ws + 0);                       // after xp-GEMM
  _Float16* sd2q = (_Float16*)(ws + 0);                       // after transpose
  _Float16* sq2d = (_Float16*)(ws + 16777216);
  float*    sxy  = (float*)   (ws + 36962304);                // after GRU
  _Float16* mbuf = (_Float16*)(ws + 36962304 + 33554432);
  _Float16* dT   = (_Float16*)(ws + 36962304 + 67108864);

  // 1) casts to f16
  cast_f2h<<<dim3(16384), dim3(256), 0, stream>>>(doc,   xd,  4194304);
  cast_f2h<<<dim3(128),   dim3(256), 0, stream>>>(ques,  xq,  32768);
  cast_f2h<<<dim3(768),   dim3(256), 0, stream>>>(wd_ih, wdI, 196608);
  cast_f2h<<<dim3(768),   dim3(256), 0, stream>>>(wq_ih, wqI, 196608);

  // 2) input transforms: xp = x @ W_ih^T + b_ih   (both directions stacked: N=1536)
  gemm_f16<<<dim3(12, 2, 1),   dim3(256), 0, stream>>>(xq, 512, 0, wqI, 512, 0, xpq, 1536, 0, 1, bq_ih, nullptr, 512);
  gemm_f16<<<dim3(12, 256, 1), dim3(256), 0, stream>>>(xd, 512, 0, wdI, 512, 0, xpd, 1536, 0, 1, bd_ih, nullptr, 512);

  // 3) GRU recurrence (writes dctx f16 over xd region, qctx f32)
  gru_k<<<dim3(18), dim3(512), 0, stream>>>(wq_hh, bq_hh, wd_hh, bd_hh, q_h0, d_h0, xpq, xpd, qctx, dctx);

  // 4) attention prep
  qprep_k<<<dim3(256), dim3(512), 0, stream>>>(qctx, wc, qwc, qT, avec);
  bvec_k<<<dim3(8192), dim3(256), 0, stream>>>(dctx, wc, bvec);

  // 5) logits sxy[n,l,q] = d_ctx . (q_ctx*wc_qd) + a[q] + b[n,l]   (f32 out)
  gemm_f16<<<dim3(2, 256, 1), dim3(256), 0, stream>>>(dctx, 512, 0, qwc, 512, 0, sxy, 256, 0, 0, avec, bvec, 512);

  // 6) d_ctx^T per sentence (needed for aq2d; must precede probs which overwrites dctx)
  transpose_k<<<dim3(16, 16, 64), dim3(256), 0, stream>>>(dctx, dT);

  // 7) softmax reductions + probability tensors (f16)
  reduce_rows<<<dim3(8192), dim3(256), 0, stream>>>(sxy, rmax, rsum);
  reduce_cols<<<dim3(64),   dim3(256), 0, stream>>>(sxy, cmax, csum);
  probs_k<<<dim3(8192), dim3(256), 0, stream>>>(sxy, rmax, rsum, cmax, csum, sd2q, sq2d);

  // 8) ad2q = sd2q @ q_ctx   -> out[:, 0:512]
  gemm_f16<<<dim3(4, 256, 1), dim3(256), 0, stream>>>(sd2q, 256, 0, qT, 256, 0, out, 1024, 0, 0, nullptr, nullptr, 256);

  // 9) m[n] = sd2q[n] @ sq2d[n]^T  (f16)
  gemm_f16<<<dim3(4, 4, 64), dim3(256), 0, stream>>>(sd2q, 256, 131072, sq2d, 256, 131072, mbuf, 512, 262144, 1, nullptr, nullptr, 256);

  // 10) aq2d[n] = m[n] @ d_ctx[n]  -> out[:, 512:1024]
  gemm_f16<<<dim3(4, 4, 64), dim3(256), 0, stream>>>(mbuf, 512, 262144, dT, 512, 262144, out + 512, 1024, 524288, 0, nullptr, nullptr, 512);
}

// Round 13
// 1226.864 us; speedup vs baseline: 1.8907x; 1.2913x over previous
//
#include <hip/hip_runtime.h>

typedef _Float16 half8  __attribute__((ext_vector_type(8)));
typedef _Float16 half4h __attribute__((ext_vector_type(4)));
typedef float    floatx4 __attribute__((ext_vector_type(4)));
typedef unsigned int uintx4 __attribute__((ext_vector_type(4)));

#define DEV __device__ __forceinline__

DEV float sigmoid_(float x) { return __builtin_amdgcn_rcpf(1.f + __expf(-x)); }
DEV float tanh_(float x) {
  float e = __expf(-2.f * fabsf(x));
  float t = (1.f - e) * __builtin_amdgcn_rcpf(1.f + e);
  return x < 0.f ? -t : t;
}

// ---------------------------------------------------------------- cast f32->f16
__global__ void cast_f2h(const float* __restrict__ in, _Float16* __restrict__ outp, int n4) {
  int i = blockIdx.x * 256 + threadIdx.x;
  if (i < n4) {
    floatx4 v = ((const floatx4*)in)[i];
    half4h o;
    o[0] = (_Float16)v[0]; o[1] = (_Float16)v[1]; o[2] = (_Float16)v[2]; o[3] = (_Float16)v[3];
    ((half4h*)outp)[i] = o;
  }
}

// ---------------------------------------------------------------- generic f16 GEMM
__launch_bounds__(256, 2)
__global__ void gemm_f16(const _Float16* __restrict__ A, int lda, long long sA,
                         const _Float16* __restrict__ Bt, int ldb, long long sB,
                         void* __restrict__ Cv, int ldc, long long sC, int c_f16,
                         const float* __restrict__ colbias,
                         const float* __restrict__ rowbias, int K)
{
  __shared__ __align__(16) _Float16 As[128 * 64];
  __shared__ __align__(16) _Float16 Bs[128 * 64];
  int m0 = blockIdx.y * 128, n0 = blockIdx.x * 128;
  int z = blockIdx.z;
  const _Float16* Ab = A + (size_t)z * sA;
  const _Float16* Bb = Bt + (size_t)z * sB;
  int tid = threadIdx.x;
  int wave = tid >> 6, lane = tid & 63;
  int ln = lane & 15, lg = lane >> 4;
  int wr = wave >> 1, wcq = wave & 1;
  int srow = wave * 32 + (lane >> 3);
  int scol = (lane & 7) * 8;
  const _Float16* ga = Ab + (size_t)(m0 + srow) * lda + scol;
  const _Float16* gb = Bb + (size_t)(n0 + srow) * ldb + scol;

  floatx4 acc[4][4];
#pragma unroll
  for (int i = 0; i < 4; ++i)
#pragma unroll
    for (int j = 0; j < 4; ++j) acc[i][j] = (floatx4){0.f, 0.f, 0.f, 0.f};

  uintx4 va[4], vb[4];
#pragma unroll
  for (int i = 0; i < 4; ++i) {
    va[i] = *(const uintx4*)(ga + (size_t)i * 8 * lda);
    vb[i] = *(const uintx4*)(gb + (size_t)i * 8 * ldb);
  }
  for (int k0 = 0; k0 < K; k0 += 64) {
#pragma unroll
    for (int i = 0; i < 4; ++i) {
      *(uintx4*)&As[(srow + i * 8) * 64 + scol] = va[i];
      *(uintx4*)&Bs[(srow + i * 8) * 64 + scol] = vb[i];
    }
    __syncthreads();
    if (k0 + 64 < K) {
#pragma unroll
      for (int i = 0; i < 4; ++i) {
        va[i] = *(const uintx4*)(ga + (size_t)i * 8 * lda + k0 + 64);
        vb[i] = *(const uintx4*)(gb + (size_t)i * 8 * ldb + k0 + 64);
      }
    }
#pragma unroll
    for (int kk = 0; kk < 64; kk += 32) {
      half8 af[4], bf[4];
#pragma unroll
      for (int i = 0; i < 4; ++i) af[i] = *(const half8*)&As[(wr * 64 + i * 16 + ln) * 64 + kk + lg * 8];
#pragma unroll
      for (int j = 0; j < 4; ++j) bf[j] = *(const half8*)&Bs[(wcq * 64 + j * 16 + ln) * 64 + kk + lg * 8];
#pragma unroll
      for (int i = 0; i < 4; ++i)
#pragma unroll
        for (int j = 0; j < 4; ++j)
          acc[i][j] = __builtin_amdgcn_mfma_f32_16x16x32_f16(af[i], bf[j], acc[i][j], 0, 0, 0);
    }
    __syncthreads();
  }
  size_t zc = (size_t)z * sC;
#pragma unroll
  for (int i = 0; i < 4; ++i) {
    int row0 = m0 + wr * 64 + i * 16 + lg * 4;
#pragma unroll
    for (int j = 0; j < 4; ++j) {
      int col = n0 + wcq * 64 + j * 16 + ln;
      float cb = colbias ? colbias[col] : 0.f;
#pragma unroll
      for (int r = 0; r < 4; ++r) {
        int row = row0 + r;
        float v = acc[i][j][r] + cb;
        if (rowbias) v += rowbias[row];
        if (c_f16) ((_Float16*)Cv)[zc + (size_t)row * ldc + col] = (_Float16)v;
        else       ((float*)Cv)[zc + (size_t)row * ldc + col] = v;
      }
    }
  }
}

// ---------------------------------------------------------------- GRU recurrence
// r11 post-mortem: AGPR file is a0..a255 (arch max) -> 384 AGPR/lane is
// impossible. Constraint set: residency needs 1536 lane-words/WG; per-wave
// AGPR cap 256; allocator budget 65536/T immune to all hints. Unique fit:
// 8 waves x 192 physical AGPRs (a0..a191) = 1536, occupancy 2 waves/SIMD
// needs total<=256/wave -> compiler VGPRs must stay <=64. So: bias in LDS,
// no builtin MFMAs (all 48/step/wave are inline-asm reading AGPR SrcB),
// compiler-visible state ~55 regs -> no spill -> allocator never touches
// AGPRs. A-reads use ln&7 (lanes 8-15 broadcast rows 0-7, branchless).
DEV floatx4 ldw_(const float* __restrict__ Whh, int n, int kt, int lg) {
  const floatx4* wp = (const floatx4*)(Whh + (size_t)n * 256 + kt * 32 + lg * 8);
  floatx4 w0 = wp[0], w1 = wp[1];
  half8 hw;
  hw[0] = (_Float16)w0[0]; hw[1] = (_Float16)w0[1]; hw[2] = (_Float16)w0[2]; hw[3] = (_Float16)w0[3];
  hw[4] = (_Float16)w1[0]; hw[5] = (_Float16)w1[1]; hw[6] = (_Float16)w1[2]; hw[7] = (_Float16)w1[3];
  union { half8 h; floatx4 f; } u; u.h = hw; return u.f;
}

#define LW(NT, KT, B0, B1, B2, B3) { floatx4 Wf = ldw_(Whh, (wave * 6 + NT) * 16 + ln, KT, lg); \
  asm volatile("v_accvgpr_write_b32 a" #B0 ", %0\n\tv_accvgpr_write_b32 a" #B1 ", %1\n\t" \
               "v_accvgpr_write_b32 a" #B2 ", %2\n\tv_accvgpr_write_b32 a" #B3 ", %3" \
   :: "v"(Wf[0]), "v"(Wf[1]), "v"(Wf[2]), "v"(Wf[3]) : "a" #B0, "a" #B1, "a" #B2, "a" #B3); }

#define MF(B0, B3, ACC) asm volatile( \
  "v_mfma_f32_16x16x32_f16 %0, %1, a[" #B0 ":" #B3 "], %0" \
  : "+v"(ACC) : "v"(af))

#define LDA(KT) (*(const half8*)&ha[lnr * 256 + ((((KT) * 4 + lg) ^ lnr) * 8)])

__launch_bounds__(512)
__global__ void gru_k(const float* __restrict__ wq_hh, const float* __restrict__ bq_hh,
                      const float* __restrict__ wd_hh, const float* __restrict__ bd_hh,
                      const float* __restrict__ q_h0v, const float* __restrict__ d_h0v,
                      const _Float16* __restrict__ xpq, const _Float16* __restrict__ xpd,
                      float* __restrict__ q_ctx, _Float16* __restrict__ d_ctx)
{
  __shared__ __align__(16) float hp[8 * 768];
  __shared__ __align__(16) float hf[8 * 256];
  __shared__ __align__(16) _Float16 ha[8 * 256];
  __shared__ __align__(16) float bl[768];

  int g = blockIdx.x;
  int isq = g >= 16;
  int dir = isq ? (g - 16) : (g >> 3);
  int sbase = isq ? 0 : (g & 7) * 8;
  int S = isq ? 1 : 8;
  int T = isq ? 256 : 512;
  const float* Whh = (isq ? wq_hh : wd_hh) + (size_t)dir * 768 * 256;
  const float* bhh = (isq ? bq_hh : bd_hh) + dir * 768;
  const float* h0  = (isq ? q_h0v : d_h0v) + dir * 256;
  const _Float16* xp = (isq ? xpq : xpd + (size_t)sbase * 512 * 1536) + dir * 768;

  int tid = threadIdx.x;
  int wave = tid >> 6, lane = tid & 63;
  int ln = lane & 15, lg = lane >> 4;
  int lnr = ln & 7;

  // weights -> physical AGPRs, base(kt,nt) = kt*24 + nt*4, a0..a191
  LW(0,0,0,1,2,3)     LW(1,0,4,5,6,7)     LW(2,0,8,9,10,11)    LW(3,0,12,13,14,15)   LW(4,0,16,17,18,19)   LW(5,0,20,21,22,23)
  LW(0,1,24,25,26,27) LW(1,1,28,29,30,31) LW(2,1,32,33,34,35)  LW(3,1,36,37,38,39)   LW(4,1,40,41,42,43)   LW(5,1,44,45,46,47)
  LW(0,2,48,49,50,51) LW(1,2,52,53,54,55) LW(2,2,56,57,58,59)  LW(3,2,60,61,62,63)   LW(4,2,64,65,66,67)   LW(5,2,68,69,70,71)
  LW(0,3,72,73,74,75) LW(1,3,76,77,78,79) LW(2,3,80,81,82,83)  LW(3,3,84,85,86,87)   LW(4,3,88,89,90,91)   LW(5,3,92,93,94,95)
  LW(0,4,96,97,98,99) LW(1,4,100,101,102,103) LW(2,4,104,105,106,107) LW(3,4,108,109,110,111) LW(4,4,112,113,114,115) LW(5,4,116,117,118,119)
  LW(0,5,120,121,122,123) LW(1,5,124,125,126,127) LW(2,5,128,129,130,131) LW(3,5,132,133,134,135) LW(4,5,136,137,138,139) LW(5,5,140,141,142,143)
  LW(0,6,144,145,146,147) LW(1,6,148,149,150,151) LW(2,6,152,153,154,155) LW(3,6,156,157,158,159) LW(4,6,160,161,162,163) LW(5,6,164,165,166,167)
  LW(0,7,168,169,170,171) LW(1,7,172,173,174,175) LW(2,7,176,177,178,179) LW(3,7,180,181,182,183) LW(4,7,184,185,186,187) LW(5,7,188,189,190,191)

  // init h (all seqs share h0); ha XOR-swizzled by 16B granule within each row
  if (tid < 256) {
    float v = h0[tid];
    _Float16 hv = (_Float16)v;
    int gq = tid >> 3, wi = tid & 7;
#pragma unroll
    for (int s = 0; s < 8; ++s) {
      hf[s * 256 + tid] = v;
      ha[s * 256 + ((gq ^ s) * 8) + wi] = hv;
    }
  }
  for (int i = tid; i < 768; i += 512) bl[i] = bhh[i];
  __syncthreads();

  int s_g = tid >> 6;
  int i0 = (tid & 63) * 4;
  int gact = tid < S * 64;
  int gq0 = i0 >> 3, gw0 = i0 & 7;
  int srow = isq ? 0 : s_g;

  for (int t = 0; t < T; ++t) {
    int teff = dir ? (T - 1 - t) : t;
    // xp loads issued early; MFMA phase hides the latency
    half4h xr_c, xz_c, xn_c;
    if (gact) {
      const _Float16* xrp = xp + ((size_t)srow * 512 + (size_t)teff) * 1536 + i0;
      xr_c = *(const half4h*)(xrp);
      xz_c = *(const half4h*)(xrp + 256);
      xn_c = *(const half4h*)(xrp + 512);
    }
    floatx4 acc[6];
#pragma unroll
    for (int nt = 0; nt < 6; ++nt) acc[nt] = (floatx4){0.f, 0.f, 0.f, 0.f};
    half8 af;
    af = LDA(0);
    MF(0,3,acc[0]);    MF(4,7,acc[1]);    MF(8,11,acc[2]);   MF(12,15,acc[3]);  MF(16,19,acc[4]);  MF(20,23,acc[5]);
    af = LDA(1);
    MF(24,27,acc[0]);  MF(28,31,acc[1]);  MF(32,35,acc[2]);  MF(36,39,acc[3]);  MF(40,43,acc[4]);  MF(44,47,acc[5]);
    af = LDA(2);
    MF(48,51,acc[0]);  MF(52,55,acc[1]);  MF(56,59,acc[2]);  MF(60,63,acc[3]);  MF(64,67,acc[4]);  MF(68,71,acc[5]);
    af = LDA(3);
    MF(72,75,acc[0]);  MF(76,79,acc[1]);  MF(80,83,acc[2]);  MF(84,87,acc[3]);  MF(88,91,acc[4]);  MF(92,95,acc[5]);
    af = LDA(4);
    MF(96,99,acc[0]);  MF(100,103,acc[1]); MF(104,107,acc[2]); MF(108,111,acc[3]); MF(112,115,acc[4]); MF(116,119,acc[5]);
    af = LDA(5);
    MF(120,123,acc[0]); MF(124,127,acc[1]); MF(128,131,acc[2]); MF(132,135,acc[3]); MF(136,139,acc[4]); MF(140,143,acc[5]);
    af = LDA(6);
    MF(144,147,acc[0]); MF(148,151,acc[1]); MF(152,155,acc[2]); MF(156,159,acc[3]); MF(160,163,acc[4]); MF(164,167,acc[5]);
    af = LDA(7);
    MF(168,171,acc[0]); MF(172,175,acc[1]); MF(176,179,acc[2]); MF(180,183,acc[3]); MF(184,187,acc[4]); MF(188,191,acc[5]);
    // MFMA(D in VGPR) -> VALU/LDS read hazard fence (data-dep keeps ordering)
    asm volatile("s_nop 7\n\ts_nop 7"
      : "+v"(acc[0]), "+v"(acc[1]), "+v"(acc[2]), "+v"(acc[3]), "+v"(acc[4]), "+v"(acc[5]));
    if (lane < 32) {  // C rows 0..7 live on lanes 0..31
#pragma unroll
      for (int nt = 0; nt < 6; ++nt) {
        int n = (wave * 6 + nt) * 16 + ln;
#pragma unroll
        for (int r = 0; r < 4; ++r)
          hp[(lg * 4 + r) * 768 + n] = acc[nt][r];
      }
    }
    __syncthreads();
    if (gact) {
      floatx4 hr4 = *(const floatx4*)&hp[s_g * 768 + i0];
      floatx4 hz4 = *(const floatx4*)&hp[s_g * 768 + 256 + i0];
      floatx4 hn4 = *(const floatx4*)&hp[s_g * 768 + 512 + i0];
      floatx4 hv4 = *(const floatx4*)&hf[s_g * 256 + i0];
      floatx4 br4 = *(const floatx4*)&bl[i0];
      floatx4 bz4 = *(const floatx4*)&bl[256 + i0];
      floatx4 bn4 = *(const floatx4*)&bl[512 + i0];
      floatx4 h2;
#pragma unroll
      for (int u = 0; u < 4; ++u) {
        float r  = sigmoid_((float)xr_c[u] + hr4[u] + br4[u]);
        float zz = sigmoid_((float)xz_c[u] + hz4[u] + bz4[u]);
        float nn = tanh_((float)xn_c[u] + r * (hn4[u] + bn4[u]));
        h2[u] = (1.f - zz) * nn + zz * hv4[u];
      }
      *(floatx4*)&hf[s_g * 256 + i0] = h2;
      half4h hh;
#pragma unroll
      for (int u = 0; u < 4; ++u) hh[u] = (_Float16)h2[u];
      *(half4h*)&ha[s_g * 256 + ((gq0 ^ s_g) * 8) + gw0] = hh;
      if (isq) {
        *(floatx4*)&q_ctx[(size_t)teff * 512 + dir * 256 + i0] = h2;
      } else {
        *(half4h*)&d_ctx[((size_t)(sbase + s_g) * 512 + (size_t)teff) * 512 + dir * 256 + i0] = hh;
      }
    }
    __syncthreads();
  }
}

// ---------------------------------------------------------------- small prep kernels
__global__ void qprep_k(const float* __restrict__ qctx, const float* __restrict__ wc,
                        _Float16* __restrict__ qwc, _Float16* __restrict__ qT, float* __restrict__ avec) {
  int q = blockIdx.x, h = threadIdx.x;  // 256 blocks x 512 threads
  float v = qctx[q * 512 + h];
  qwc[q * 512 + h] = (_Float16)(v * wc[1024 + h]);
  qT[h * 256 + q] = (_Float16)v;
  float p = v * wc[h];
  __shared__ float red[8];
#pragma unroll
  for (int o = 32; o; o >>= 1) p += __shfl_xor(p, o);
  if ((h & 63) == 0) red[h >> 6] = p;
  __syncthreads();
  if (h < 8) {
    float tt = red[h];
#pragma unroll
    for (int o = 4; o; o >>= 1) tt += __shfl_xor(tt, o);
    if (h == 0) avec[q] = tt;
  }
}

__global__ void bvec_k(const _Float16* __restrict__ dctx, const float* __restrict__ wc, float* __restrict__ bv) {
  int row = blockIdx.x * 4 + (threadIdx.x >> 6);
  int lane = threadIdx.x & 63;
  const _Float16* p = dctx + (size_t)row * 512;
  float s = 0.f;
#pragma unroll
  for (int i = 0; i < 8; ++i) s += (float)p[lane + i * 64] * wc[512 + lane + i * 64];
#pragma unroll
  for (int o = 32; o; o >>= 1) s += __shfl_xor(s, o);
  if (lane == 0) bv[row] = s;
}

__global__ void reduce_rows(const float* __restrict__ sxy, float* __restrict__ rmax, float* __restrict__ rsum) {
  int row = blockIdx.x * 4 + (threadIdx.x >> 6);
  int lane = threadIdx.x & 63;
  const float* p = sxy + (size_t)row * 256;
  float v0 = p[lane], v1 = p[lane + 64], v2 = p[lane + 128], v3 = p[lane + 192];
  float m = fmaxf(fmaxf(v0, v1), fmaxf(v2, v3));
#pragma unroll
  for (int o = 32; o; o >>= 1) m = fmaxf(m, __shfl_xor(m, o));
  float s = __expf(v0 - m) + __expf(v1 - m) + __expf(v2 - m) + __expf(v3 - m);
#pragma unroll
  for (int o = 32; o; o >>= 1) s += __shfl_xor(s, o);
  if (lane == 0) { rmax[row] = m; rsum[row] = s; }
}

__global__ void reduce_cols(const float* __restrict__ sxy, float* __restrict__ cmax, float* __restrict__ csum) {
  int n = blockIdx.x, q = threadIdx.x;  // 64 x 256
  const float* p = sxy + (size_t)n * 131072 + q;
  float m = -3.0e38f, s = 0.f;
  for (int l = 0; l < 512; l += 4) {
    float v0 = p[(size_t)l * 256], v1 = p[(size_t)(l + 1) * 256];
    float v2 = p[(size_t)(l + 2) * 256], v3 = p[(size_t)(l + 3) * 256];
    float m4 = fmaxf(fmaxf(v0, v1), fmaxf(v2, v3));
    float nm = fmaxf(m, m4);
    s = s * __expf(m - nm) + __expf(v0 - nm) + __expf(v1 - nm) + __expf(v2 - nm) + __expf(v3 - nm);
    m = nm;
  }
  cmax[n * 256 + q] = m;
  csum[n * 256 + q] = s;
}

__global__ void probs_k(const float* __restrict__ sxy, const float* __restrict__ rmax, const float* __restrict__ rsum,
                        const float* __restrict__ cmax, const float* __restrict__ csum,
                        _Float16* __restrict__ sd2q, _Float16* __restrict__ sq2d) {
  size_t e4 = ((size_t)blockIdx.x * 256 + threadIdx.x) * 4;
  size_t r = e4 >> 8;
  size_t n = e4 >> 17;
  int q0 = (int)(e4 & 255);
  floatx4 v = *(const floatx4*)&sxy[e4];
  float rm = rmax[r], ri = 1.f / rsum[r];
  floatx4 cm = *(const floatx4*)&cmax[(n << 8) + q0];
  floatx4 cs = *(const floatx4*)&csum[(n << 8) + q0];
  half4h o1, o2;
#pragma unroll
  for (int u = 0; u < 4; ++u) {
    o1[u] = (_Float16)(__expf(v[u] - rm) * ri);
    o2[u] = (_Float16)(__expf(v[u] - cm[u]) / cs[u]);
  }
  *(half4h*)&sd2q[e4] = o1;
  *(half4h*)&sq2d[e4] = o2;
}

__global__ void transpose_k(const _Float16* __restrict__ in, _Float16* __restrict__ outp) {
  __shared__ _Float16 tile[32][33];
  int nz = blockIdx.z;
  int l0 = blockIdx.x * 32, h0 = blockIdx.y * 32;
  const _Float16* ip = in + (size_t)nz * 262144;
  _Float16* op = outp + (size_t)nz * 262144;
  int x = threadIdx.x & 31, y = threadIdx.x >> 5;
#pragma unroll
  for (int i = 0; i < 4; ++i) tile[y + i * 8][x] = ip[(size_t)(l0 + y + i * 8) * 512 + h0 + x];
  __syncthreads();
#pragma unroll
  for (int i = 0; i < 4; ++i) op[(size_t)(h0 + y + i * 8) * 512 + l0 + x] = tile[x][y + i * 8];
}

// ---------------------------------------------------------------- launch
extern "C" void kernel_launch(void* const* d_in, const int* in_sizes, int n_in,
                              void* d_out, int out_size, void* d_ws, size_t ws_size,
                              hipStream_t stream) {
  const float* doc   = (const float*)d_in[0];
  const float* ques  = (const float*)d_in[1];
  const float* q_h0  = (const float*)d_in[2];
  const float* d_h0  = (const float*)d_in[3];
  const float* wq_ih = (const float*)d_in[4];
  const float* wq_hh = (const float*)d_in[5];
  const float* bq_ih = (const float*)d_in[6];
  const float* bq_hh = (const float*)d_in[7];
  const float* wd_ih = (const float*)d_in[8];
  const float* wd_hh = (const float*)d_in[9];
  const float* bd_ih = (const float*)d_in[10];
  const float* bd_hh = (const float*)d_in[11];
  const float* wc    = (const float*)d_in[12];
  float* out = (float*)d_out;
  char* ws = (char*)d_ws;

  // workspace layout (peak ~133.5 MiB, regions reused over time)
  _Float16* xd   = (_Float16*)(ws + 0);            // 33,554,432 B  (later: dctx, then sd2q|sq2d)
  _Float16* xq   = (_Float16*)(ws + 33554432);     //    262,144
  _Float16* wdI  = (_Float16*)(ws + 33816576);     //  1,572,864
  _Float16* wqI  = (_Float16*)(ws + 35389440);     //  1,572,864
  _Float16* xpd  = (_Float16*)(ws + 36962304);     // 100,663,296  (later: sxy | mbuf | dT)
  _Float16* xpq  = (_Float16*)(ws + 137625600);    //    786,432
  float*    qctx = (float*)   (ws + 138412032);    //    524,288
  _Float16* qT   = (_Float16*)(ws + 138936320);    //    262,144
  _Float16* qwc  = (_Float16*)(ws + 139198464);    //    262,144
  float*    avec = (float*)   (ws + 139460608);    //      1,024
  float*    bvec = (float*)   (ws + 139461632);    //    131,072
  float*    rmax = (float*)   (ws + 139592704);    //    131,072
  float*    rsum = (float*)   (ws + 139723776);    //    131,072
  float*    cmax = (float*)   (ws + 139854848);    //     65,536
  float*    csum = (float*)   (ws + 139920384);    //     65,536
  // aliases
  _Float16* dctx = (_Float16*)(ws + 0);                       // after xp-GEMM
  _Float16* sd2q = (_Float16*)(ws + 0);                       // after transpose
  _Float16* sq2d = (_Float16*)(ws + 16777216);
  float*    sxy  = (float*)   (ws + 36962304);                // after GRU
  _Float16* mbuf = (_Float16*)(ws + 36962304 + 33554432);
  _Float16* dT   = (_Float16*)(ws + 36962304 + 67108864);

  // 1) casts to f16
  cast_f2h<<<dim3(16384), dim3(256), 0, stream>>>(doc,   xd,  4194304);
  cast_f2h<<<dim3(128),   dim3(256), 0, stream>>>(ques,  xq,  32768);
  cast_f2h<<<dim3(768),   dim3(256), 0, stream>>>(wd_ih, wdI, 196608);
  cast_f2h<<<dim3(768),   dim3(256), 0, stream>>>(wq_ih, wqI, 196608);

  // 2) input transforms: xp = x @ W_ih^T + b_ih   (both directions stacked: N=1536)
  gemm_f16<<<dim3(12, 2, 1),   dim3(256), 0, stream>>>(xq, 512, 0, wqI, 512, 0, xpq, 1536, 0, 1, bq_ih, nullptr, 512);
  gemm_f16<<<dim3(12, 256, 1), dim3(256), 0, stream>>>(xd, 512, 0, wdI, 512, 0, xpd, 1536, 0, 1, bd_ih, nullptr, 512);

  // 3) GRU recurrence (writes dctx f16 over xd region, qctx f32)
  gru_k<<<dim3(18), dim3(512), 0, stream>>>(wq_hh, bq_hh, wd_hh, bd_hh, q_h0, d_h0, xpq, xpd, qctx, dctx);

  // 4) attention prep
  qprep_k<<<dim3(256), dim3(512), 0, stream>>>(qctx, wc, qwc, qT, avec);
  bvec_k<<<dim3(8192), dim3(256), 0, stream>>>(dctx, wc, bvec);

  // 5) logits sxy[n,l,q] = d_ctx . (q_ctx*wc_qd) + a[q] + b[n,l]   (f32 out)
  gemm_f16<<<dim3(2, 256, 1), dim3(256), 0, stream>>>(dctx, 512, 0, qwc, 512, 0, sxy, 256, 0, 0, avec, bvec, 512);

  // 6) d_ctx^T per sentence (needed for aq2d; must precede probs which overwrites dctx)
  transpose_k<<<dim3(16, 16, 64), dim3(256), 0, stream>>>(dctx, dT);

  // 7) softmax reductions + probability tensors (f16)
  reduce_rows<<<dim3(8192), dim3(256), 0, stream>>>(sxy, rmax, rsum);
  reduce_cols<<<dim3(64),   dim3(256), 0, stream>>>(sxy, cmax, csum);
  probs_k<<<dim3(8192), dim3(256), 0, stream>>>(sxy, rmax, rsum, cmax, csum, sd2q, sq2d);

  // 8) ad2q = sd2q @ q_ctx   -> out[:, 0:512]
  gemm_f16<<<dim3(4, 256, 1), dim3(256), 0, stream>>>(sd2q, 256, 0, qT, 256, 0, out, 1024, 0, 0, nullptr, nullptr, 256);

  // 9) m[n] = sd2q[n] @ sq2d[n]^T  (f16)
  gemm_f16<<<dim3(4, 4, 64), dim3(256), 0, stream>>>(sd2q, 256, 131072, sq2d, 256, 131072, mbuf, 512, 262144, 1, nullptr, nullptr, 256);

  // 10) aq2d[n] = m[n] @ d_ctx[n]  -> out[:, 512:1024]
  gemm_f16<<<dim3(4, 4, 64), dim3(256), 0, stream>>>(mbuf, 512, 262144, dT, 512, 262144, out + 512, 1024, 524288, 0, nullptr, nullptr, 512);
}